// Round 1
// 1185.162 us; speedup vs baseline: 1.1515x; 1.1515x over previous
//
#include <hip/hip_runtime.h>

// Problem constants (fixed by setup_inputs).
constexpr int N_NODES = 40960;
constexpr int E_EDGES = 131072;
constexpr int B_GRAPH = 1024;
constexpr int FXD  = 78;
constexpr int FXD2 = 156;
constexpr int FXD4 = 312;
constexpr int OD   = 128;
constexpr int FXT  = 37261;
constexpr int KP   = 37280;            // FXT padded to mult of 32
constexpr int NPG  = N_NODES / B_GRAPH;
constexpr int NN2  = 2 * N_NODES;      // batched (both drug branches)
constexpr int EE2  = 2 * E_EDGES;

typedef unsigned short us16;
typedef __attribute__((ext_vector_type(8))) short short8;  // 8 bf16
typedef __attribute__((ext_vector_type(4))) float f32x4;

__device__ inline us16 f2bf(float f) {             // fp32 -> bf16 RNE
    unsigned u = __float_as_uint(f);
    return (us16)((u + 0x7FFF + ((u >> 16) & 1)) >> 16);
}
__device__ inline float ldf(const float* p) { return *p; }
__device__ inline float ldf(const us16* p) { return __uint_as_float(((unsigned)*p) << 16); }

// ---------------------------------------------------------------------------
// Cell-layer bf16 MFMA GEMM: cv1[1024x512] += An[1024xKP] @ BwT^T.
// 128x128 tile, BK=32, split-K z=32, register-prefetch pipeline.
// ---------------------------------------------------------------------------
__global__ __launch_bounds__(256, 2)
void mfma_cell_gemm(const us16* __restrict__ An, const us16* __restrict__ BwT,
                    float* __restrict__ C)
{
    __shared__ us16 As[128][40];
    __shared__ us16 Bs[128][40];
    const int tid = threadIdx.x;
    const int m0 = blockIdx.x * 128;          // gx = 8
    const int n0 = blockIdx.y * 128;          // gy = 4
    const int S  = KP / 32;                   // 1165
    const int per = (S + gridDim.z - 1) / gridDim.z;
    const int s0 = blockIdx.z * per;
    const int s1 = min(S, s0 + per);

    const int r = tid >> 1;
    const int h = (tid & 1) * 16;

    const us16* Ap = An  + (size_t)(m0 + r) * KP + s0 * 32 + h;
    const us16* Bp = BwT + (size_t)(n0 + r) * KP + s0 * 32 + h;

    const int wave = tid >> 6, lane = tid & 63;
    const int wm = (wave >> 1) * 64, wn = (wave & 1) * 64;
    const int fr = lane & 15, fq = (lane >> 4) * 8;

    f32x4 acc[4][4] = {};
    uint4 pa0, pa1, pb0, pb1;
    if (s0 < s1) {
        pa0 = *(const uint4*)Ap;       pa1 = *(const uint4*)(Ap + 8);
        pb0 = *(const uint4*)Bp;       pb1 = *(const uint4*)(Bp + 8);
    }
    for (int s = s0; s < s1; ++s) {
        __syncthreads();
        *(uint4*)&As[r][h] = pa0;  *(uint4*)&As[r][h + 8] = pa1;
        *(uint4*)&Bs[r][h] = pb0;  *(uint4*)&Bs[r][h + 8] = pb1;
        __syncthreads();
        if (s + 1 < s1) {           // prefetch next iter; latency hides behind MFMA
            Ap += 32; Bp += 32;
            pa0 = *(const uint4*)Ap;  pa1 = *(const uint4*)(Ap + 8);
            pb0 = *(const uint4*)Bp;  pb1 = *(const uint4*)(Bp + 8);
        }
        short8 af[4], bf[4];
#pragma unroll
        for (int t = 0; t < 4; ++t) {
            af[t] = *(const short8*)&As[wm + t * 16 + fr][fq];
            bf[t] = *(const short8*)&Bs[wn + t * 16 + fr][fq];
        }
#pragma unroll
        for (int mt = 0; mt < 4; ++mt)
#pragma unroll
            for (int nt = 0; nt < 4; ++nt)
                acc[mt][nt] = __builtin_amdgcn_mfma_f32_16x16x32_bf16(
                    af[mt], bf[nt], acc[mt][nt], 0, 0, 0);
    }
#pragma unroll
    for (int mt = 0; mt < 4; ++mt)
#pragma unroll
        for (int nt = 0; nt < 4; ++nt)
#pragma unroll
            for (int reg = 0; reg < 4; ++reg) {
                int row = m0 + wm + mt * 16 + (lane >> 4) * 4 + reg;
                int col = n0 + wn + nt * 16 + fr;
                atomicAdd(&C[(size_t)row * 512 + col], acc[mt][nt][reg]);
            }
}

// An[row][k] = bf16(cell[row][k] * invn[row]), zero-padded to KP.
__global__ void convert_cell(const float* __restrict__ cell, const float* __restrict__ invn,
                             us16* __restrict__ An)
{
    const int row = blockIdx.y;
    const int k8 = (blockIdx.x * 256 + threadIdx.x) * 8;
    if (k8 >= KP) return;
    const float s = invn[row];
    const float* src = cell + (size_t)row * FXT;
    us16 v[8];
#pragma unroll
    for (int j = 0; j < 8; ++j) {
        int k = k8 + j;
        v[j] = f2bf((k < FXT) ? src[k] * s : 0.0f);
    }
    *(uint4*)&An[(size_t)row * KP + k8] = *(uint4*)v;
}

// WT[n][k] = bf16(W[k][n]), k zero-padded to KPc. 32x32 tiled transpose.
__global__ __launch_bounds__(256)
void convert_wT(const float* __restrict__ W, us16* __restrict__ WT,
                int K, int Nn, int KPc)
{
    __shared__ float tile[32][33];
    const int k0 = blockIdx.x * 32;
    const int n0 = blockIdx.y * 32;
    const int c  = threadIdx.x & 31;
    const int r0 = threadIdx.x >> 5;
#pragma unroll
    for (int p = 0; p < 4; ++p) {
        int k = k0 + r0 + p * 8;
        tile[r0 + p * 8][c] = (k < K && n0 + c < Nn) ? W[(size_t)k * Nn + n0 + c] : 0.0f;
    }
    __syncthreads();
#pragma unroll
    for (int p = 0; p < 4; ++p) {
        int n = n0 + r0 + p * 8;
        if (n < Nn) WT[(size_t)n * KPc + k0 + c] = f2bf(tile[c][r0 + p * 8]);
    }
}

// Small padded weight transpose: WT[n][k] bf16, n in [0,NPr), k in [0,KPc),
// zero-filled outside the real K x Nn extent. Tiny matrices only.
__global__ void convert_wT_small(const float* __restrict__ W, us16* __restrict__ WT,
                                 int K, int Nn, int KPc, int NPr)
{
    int idx = blockIdx.x * 256 + threadIdx.x;
    if (idx >= NPr * KPc) return;
    int n = idx / KPc, k = idx - n * KPc;
    WT[idx] = (n < Nn && k < K) ? f2bf(W[(size_t)k * Nn + n]) : (us16)0;
}

// ---------------------------------------------------------------------------
// Drug-conv bf16 MFMA GEMM: C = relu(A @ WT^T + bias), bf16 out.
// A: [NN2][KA] bf16 (zero-padded K). WT: [NP][KA] bf16 (zero-padded rows).
// Block: 256 thr / 4 waves; BM=128 (wave=32 rows); NTILE=80 (5 n-frags).
// Whole B tile in LDS; A double-buffered per 32-k step.
// ---------------------------------------------------------------------------
template<int KA>
__global__ __launch_bounds__(256, 2)
void mfma_conv(const us16* __restrict__ A, const us16* __restrict__ BT,
               const float* __restrict__ bias, us16* __restrict__ C,
               int Nn, int ldc)
{
    constexpr int KS = KA / 32;
    __shared__ us16 As[2][128][40];
    __shared__ us16 Bs[80][KA + 8];
    const int tid = threadIdx.x;
    const int m0 = blockIdx.x * 128;
    const int n0 = blockIdx.y * 80;

    // B tile (80 x KA), read-once (hot in L2 across blocks)
    for (int idx = tid; idx < 80 * (KA / 8); idx += 256) {
        int nr = idx / (KA / 8), c8 = (idx - nr * (KA / 8)) * 8;
        *(uint4*)&Bs[nr][c8] = *(const uint4*)&BT[(size_t)(n0 + nr) * KA + c8];
    }

    const int r = tid >> 1, h = (tid & 1) * 16;
    const us16* Ap = A + (size_t)(m0 + r) * KA + h;
    *(uint4*)&As[0][r][h]     = *(const uint4*)Ap;
    *(uint4*)&As[0][r][h + 8] = *(const uint4*)(Ap + 8);
    __syncthreads();

    const int wave = tid >> 6, lane = tid & 63;
    const int wm = wave * 32;
    const int fr = lane & 15, fq = (lane >> 4) * 8;

    f32x4 acc[2][5] = {};
#pragma unroll
    for (int s = 0; s < KS; ++s) {
        const int cb = s & 1;
        if (s + 1 < KS) {                    // prefetch next chunk into other buffer
            uint4 t0 = *(const uint4*)(Ap + 32);
            uint4 t1 = *(const uint4*)(Ap + 40);
            Ap += 32;
            *(uint4*)&As[cb ^ 1][r][h]     = t0;
            *(uint4*)&As[cb ^ 1][r][h + 8] = t1;
        }
        short8 af[2], bf[5];
#pragma unroll
        for (int mt = 0; mt < 2; ++mt)
            af[mt] = *(const short8*)&As[cb][wm + mt * 16 + fr][fq];
#pragma unroll
        for (int nf = 0; nf < 5; ++nf)
            bf[nf] = *(const short8*)&Bs[nf * 16 + fr][s * 32 + fq];
#pragma unroll
        for (int mt = 0; mt < 2; ++mt)
#pragma unroll
            for (int nf = 0; nf < 5; ++nf)
                acc[mt][nf] = __builtin_amdgcn_mfma_f32_16x16x32_bf16(
                    af[mt], bf[nf], acc[mt][nf], 0, 0, 0);
        __syncthreads();
    }

#pragma unroll
    for (int mt = 0; mt < 2; ++mt)
#pragma unroll
        for (int nf = 0; nf < 5; ++nf) {
            const int col = n0 + nf * 16 + fr;
            if (col < Nn) {
                const float bv = bias[col];
#pragma unroll
                for (int reg = 0; reg < 4; ++reg) {
                    int row = m0 + wm + mt * 16 + (lane >> 4) * 4 + reg;
                    C[(size_t)row * ldc + col] = f2bf(fmaxf(acc[mt][nf][reg] + bv, 0.0f));
                }
            }
        }
}

// ---------------------------------------------------------------------------
// Batched (both graphs) edge sort + gather aggregation.
// ---------------------------------------------------------------------------
__global__ void deg_count_b(const int* __restrict__ ei1, const int* __restrict__ ei2,
                            int* cnt) {
    int i = blockIdx.x * blockDim.x + threadIdx.x;
    if (i >= EE2) return;
    int d = (i < E_EDGES) ? ei1[E_EDGES + i] : ei2[E_EDGES + (i - E_EDGES)] + N_NODES;
    atomicAdd(&cnt[d], 1);
}

__global__ __launch_bounds__(512)
void scan1(const int* __restrict__ cnt, int* base, int* aux, float* dinv) {
    __shared__ int s[512];
    const int tid = threadIdx.x;
    const int i = blockIdx.x * 512 + tid;
    int v = cnt[i];
    dinv[i] = rsqrtf((float)(v + 1));
    s[tid] = v;
    __syncthreads();
    for (int off = 1; off < 512; off <<= 1) {
        int t = (tid >= off) ? s[tid - off] : 0;
        __syncthreads();
        s[tid] += t;
        __syncthreads();
    }
    base[i] = s[tid] - v;
    if (tid == 511) aux[blockIdx.x] = s[511];
}

__global__ void scan2(int* aux, int nblk) {
    __shared__ int s[256];
    const int tid = threadIdx.x;
    int v = (tid < nblk) ? aux[tid] : 0;
    s[tid] = v;
    __syncthreads();
    for (int off = 1; off < 256; off <<= 1) {
        int t = (tid >= off) ? s[tid - off] : 0;
        __syncthreads();
        s[tid] += t;
        __syncthreads();
    }
    if (tid < nblk) aux[tid] = s[tid] - v;
}

__global__ __launch_bounds__(512)
void scan3(int* base, const int* __restrict__ aux) {
    int i = blockIdx.x * 512 + threadIdx.x;
    base[i] += aux[blockIdx.x];
    if (i == 0) base[NN2] = EE2;
}

__global__ void place_edges_b(const int* __restrict__ ei1, const int* __restrict__ ei2,
                              const float* __restrict__ dinv, const int* __restrict__ base,
                              int* cur, int* __restrict__ esrc, float* __restrict__ enorm) {
    int e = blockIdx.x * blockDim.x + threadIdx.x;
    if (e >= EE2) return;
    int s, d;
    if (e < E_EDGES) { s = ei1[e];            d = ei1[E_EDGES + e]; }
    else             { s = ei2[e - E_EDGES] + N_NODES;
                       d = ei2[E_EDGES + (e - E_EDGES)] + N_NODES; }
    int p = base[d] + atomicAdd(&cur[d], 1);
    esrc[p]  = s;
    enorm[p] = dinv[s] * dinv[d];
}

// out[row][0:kaout] = bf16( sum_edges h[src]*norm + h[row]*dinv^2 ), zero pad.
template<typename Tin, int CH>
__global__ __launch_bounds__(256)
void gather_bf(const Tin* __restrict__ hA, const Tin* __restrict__ hB, int st, int fi, int kaout,
               const float* __restrict__ dinv, const int* __restrict__ base,
               const int* __restrict__ esrc, const float* __restrict__ enorm,
               us16* __restrict__ out)
{
    const int row  = blockIdx.x * 4 + (threadIdx.x >> 6);
    const int lane = threadIdx.x & 63;
    const float d  = dinv[row];
    const float d2 = d * d;
    const Tin* hr = (row < N_NODES) ? hA + (size_t)row * st
                                    : hB + (size_t)(row - N_NODES) * st;
    float acc[CH];
#pragma unroll
    for (int c = 0; c < CH; ++c) {
        int f = lane + 64 * c;
        acc[c] = (f < fi) ? ldf(hr + f) * d2 : 0.0f;
    }
    const int b0 = base[row], b1 = base[row + 1];
    for (int j = b0; j < b1; ++j) {
        const int s = esrc[j];
        const float w = enorm[j];
        const Tin* hs = (s < N_NODES) ? hA + (size_t)s * st
                                      : hB + (size_t)(s - N_NODES) * st;
#pragma unroll
        for (int c = 0; c < CH; ++c) {
            int f = lane + 64 * c;
            if (f < fi) acc[c] = fmaf(ldf(hs + f), w, acc[c]);
        }
    }
    us16* orow = out + (size_t)row * kaout;
#pragma unroll
    for (int c = 0; c < CH; ++c) {
        int f = lane + 64 * c;
        if (f < kaout) orow[f] = f2bf(acc[c]);   // acc==0 for f>=fi -> zero pad
    }
}

// ---------------------------------------------------------------------------
__global__ void seg_max_bf(const us16* __restrict__ x, float* __restrict__ out,
                           int fo, int ld) {
    int f = blockIdx.x * blockDim.x + threadIdx.x;
    int g = blockIdx.y;
    if (f >= fo) return;
    const us16* xp = x + (size_t)g * NPG * ld + f;
    float v = -1e30f;
#pragma unroll 4
    for (int j = 0; j < NPG; ++j) v = fmaxf(v, ldf(xp + (size_t)j * ld));
    out[(size_t)g * fo + f] = v;
}

__global__ __launch_bounds__(256)
void row_invnorm(const float* __restrict__ cell, float* __restrict__ invn, int K) {
    int b = blockIdx.x;
    const float* row = cell + (size_t)b * K;
    float ss = 0.f;
    for (int k = threadIdx.x; k < K; k += 256) {
        float v = row[k];
        ss = fmaf(v, v, ss);
    }
    for (int off = 32; off > 0; off >>= 1) ss += __shfl_down(ss, off, 64);
    __shared__ float sred[4];
    int lane = threadIdx.x & 63, wv = threadIdx.x >> 6;
    if (lane == 0) sred[wv] = ss;
    __syncthreads();
    if (threadIdx.x == 0) {
        float nrm = sqrtf(sred[0] + sred[1] + sred[2] + sred[3]);
        invn[b] = 1.0f / fmaxf(nrm, 1e-12f);
    }
}

// C = act(A@B + bias). pre != null (K pow2): relu(A+pre) fused on load.
// half_off == 0: plain row addressing (rows can exceed 1024).
// half_off != 0: rows >= 1024 map to row-1024, column offset half_off.
template<bool RELU>
__global__ __launch_bounds__(256)
void gemv_rows4(const float* __restrict__ A, const float* __restrict__ B,
                const float* __restrict__ bias, const float* __restrict__ pre,
                float* __restrict__ C, int K, int N, int ldc, int half_off)
{
    __shared__ float As[4 * 512];
    const int tid = threadIdx.x;
    const int r0 = blockIdx.x * 4;
    if (pre) {
        for (int i = tid; i < 4 * K; i += 256)
            As[i] = fmaxf(A[(size_t)r0 * K + i] + pre[i & (K - 1)], 0.0f);
    } else {
        for (int i = tid; i < 4 * K; i += 256) As[i] = A[(size_t)r0 * K + i];
    }
    __syncthreads();
    float* Cb;
    if (half_off != 0)
        Cb = C + (size_t)(r0 & 1023) * ldc + ((r0 >= 1024) ? half_off : 0);
    else
        Cb = C + (size_t)r0 * ldc;
    for (int n = tid; n < N; n += 256) {
        float b0 = bias[n];
        float a0 = b0, a1 = b0, a2 = b0, a3 = b0;
        const float* Bp = B + n;
        for (int k = 0; k < K; ++k) {
            float b = Bp[(size_t)k * N];
            a0 = fmaf(As[k], b, a0);
            a1 = fmaf(As[K + k], b, a1);
            a2 = fmaf(As[2 * K + k], b, a2);
            a3 = fmaf(As[3 * K + k], b, a3);
        }
        if (RELU) { a0 = fmaxf(a0, 0.f); a1 = fmaxf(a1, 0.f); a2 = fmaxf(a2, 0.f); a3 = fmaxf(a3, 0.f); }
        Cb[0 * ldc + n] = a0;
        Cb[1 * ldc + n] = a1;
        Cb[2 * ldc + n] = a2;
        Cb[3 * ldc + n] = a3;
    }
}

__global__ void final_linear2(const float* __restrict__ x, const float* __restrict__ W,
                              const float* __restrict__ b, float* __restrict__ out) {
    int i = blockIdx.x * blockDim.x + threadIdx.x;
    if (i >= B_GRAPH * 2) return;
    int row = i >> 1, o = i & 1;
    const float* xr = x + (size_t)row * 128;
    float acc = b[o];
    for (int k = 0; k < 128; ++k) acc = fmaf(xr[k], W[k * 2 + o], acc);
    out[i] = acc;
}

// ---------------------------------------------------------------------------
extern "C" void kernel_launch(void* const* d_in, const int* in_sizes, int n_in,
                              void* d_out, int out_size, void* d_ws, size_t ws_size,
                              hipStream_t stream) {
    (void)in_sizes; (void)n_in; (void)out_size; (void)ws_size;
    const float* x1   = (const float*)d_in[0];
    const int*   ei1  = (const int*)d_in[1];
    const float* x2   = (const float*)d_in[3];
    const int*   ei2  = (const int*)d_in[4];
    const float* cell = (const float*)d_in[6];
    const float* Wc1 = (const float*)d_in[7];  const float* bc1 = (const float*)d_in[8];
    const float* Wc2 = (const float*)d_in[9];  const float* bc2 = (const float*)d_in[10];
    const float* Wc3 = (const float*)d_in[11]; const float* bc3 = (const float*)d_in[12];
    const float* Wg1 = (const float*)d_in[13]; const float* bg1 = (const float*)d_in[14];
    const float* Wg2 = (const float*)d_in[15]; const float* bg2 = (const float*)d_in[16];
    const float* Wr1 = (const float*)d_in[17]; const float* br1 = (const float*)d_in[18];
    const float* Wr2 = (const float*)d_in[19]; const float* br2 = (const float*)d_in[20];
    const float* Wr3 = (const float*)d_in[21]; const float* br3 = (const float*)d_in[22];
    const float* Wf1 = (const float*)d_in[23]; const float* bf1 = (const float*)d_in[24];
    const float* Wf2 = (const float*)d_in[25]; const float* bf2 = (const float*)d_in[26];
    const float* Wo  = (const float*)d_in[27]; const float* bo  = (const float*)d_in[28];
    float* out = (float*)d_out;

    // ---- workspace: persistent (~11.5 MB) + union region ----
    float* ws = (float*)d_ws;
    float* xc   = ws;  ws += (size_t)B_GRAPH * 384;
    float* invn = ws;  ws += B_GRAPH;
    float* cv1  = ws;  ws += (size_t)B_GRAPH * 512;
    float* cv2  = ws;  ws += (size_t)B_GRAPH * 256;
    float* f1   = ws;  ws += (size_t)B_GRAPH * 512;
    float* f2   = ws;  ws += (size_t)B_GRAPH * 128;
    float* dinv = ws;  ws += NN2;
    float* pool = ws;  ws += (size_t)2048 * FXD4;
    float* gb   = ws;  ws += (size_t)2048 * FXD2;

    // union A: cell phase bf16 buffers (1536 x KP bf16 = 114.5 MB)
    us16* An  = (us16*)ws;
    us16* BwT = An + (size_t)B_GRAPH * KP;

    // union B: branch phase (used strictly after mfma_cell_gemm; ~81 MB)
    us16* Abuf = (us16*)ws;                        // gather out, NN2 x <=160 bf16
    us16* Hbuf = Abuf + (size_t)NN2 * 160;         // conv out,  NN2 x <=320 bf16
    us16* W1T  = Hbuf + (size_t)NN2 * 320;         // 80  x 96  (16B-aligned)
    us16* W2T  = W1T + 80 * 96;                    // 160 x 96
    us16* W3T  = W2T + 160 * 96;                   // 320 x 160
    float* enorm = (float*)(W3T + 320 * 160);
    int* cnt  = (int*)(enorm + EE2);
    int* cur  = cnt + NN2;
    int* base = cur + NN2;
    int* aux  = base + NN2 + 1;
    int* esrc = aux + 256;

    // ================= cell branch (bf16 MFMA) =================
    row_invnorm<<<B_GRAPH, 256, 0, stream>>>(cell, invn, FXT);
    convert_cell<<<dim3((KP / 8 + 255) / 256, B_GRAPH, 1), 256, 0, stream>>>(cell, invn, An);
    convert_wT<<<dim3(KP / 32, 512 / 32, 1), 256, 0, stream>>>(Wr1, BwT, FXT, 512, KP);
    hipMemsetAsync(cv1, 0, (size_t)B_GRAPH * 512 * sizeof(float), stream);
    mfma_cell_gemm<<<dim3(8, 4, 32), 256, 0, stream>>>(An, BwT, cv1);
    // bias+relu on cv1 fused into the next gemv's A load (pre=br1, K=512 pow2)
    gemv_rows4<true><<<B_GRAPH / 4, 256, 0, stream>>>(cv1, Wr2, br2, br1, cv2, 512, 256, 256, 0);
    gemv_rows4<false><<<B_GRAPH / 4, 256, 0, stream>>>(cv2, Wr3, br3, nullptr, xc + 256, 256, OD, 384, 0);

    // ================= drug branches (batched, bf16 MFMA convs) =================
    hipMemsetAsync(cnt, 0, (size_t)2 * NN2 * sizeof(int), stream);   // cnt + cur
    deg_count_b<<<(EE2 + 255) / 256, 256, 0, stream>>>(ei1, ei2, cnt);
    scan1<<<NN2 / 512, 512, 0, stream>>>(cnt, base, aux, dinv);
    scan2<<<1, 256, 0, stream>>>(aux, NN2 / 512);
    scan3<<<NN2 / 512, 512, 0, stream>>>(base, aux);
    place_edges_b<<<(EE2 + 255) / 256, 256, 0, stream>>>(ei1, ei2, dinv, base, cur, esrc, enorm);

    // conv weights -> padded bf16 WT[n][k] (tiny; after cell phase frees union)
    convert_wT_small<<<(80 * 96 + 255) / 256, 256, 0, stream>>>(Wc1, W1T, FXD, FXD, 96, 80);
    convert_wT_small<<<(160 * 96 + 255) / 256, 256, 0, stream>>>(Wc2, W2T, FXD, FXD2, 96, 160);
    convert_wT_small<<<(320 * 160 + 255) / 256, 256, 0, stream>>>(Wc3, W3T, FXD2, FXD4, 160, 320);

    // conv1: gather(x) -> Abuf[96]; relu(Abuf@Wc1+bc1) -> Hbuf[80]
    gather_bf<float, 2><<<NN2 / 4, 256, 0, stream>>>(x1, x2, FXD, FXD, 96,
                                                     dinv, base, esrc, enorm, Abuf);
    mfma_conv<96><<<dim3(NN2 / 128, 1, 1), 256, 0, stream>>>(Abuf, W1T, bc1, Hbuf, FXD, 80);
    // conv2
    gather_bf<us16, 2><<<NN2 / 4, 256, 0, stream>>>(Hbuf, Hbuf + (size_t)N_NODES * 80, 80, FXD, 96,
                                                    dinv, base, esrc, enorm, Abuf);
    mfma_conv<96><<<dim3(NN2 / 128, 2, 1), 256, 0, stream>>>(Abuf, W2T, bc2, Hbuf, FXD2, 160);
    // conv3
    gather_bf<us16, 3><<<NN2 / 4, 256, 0, stream>>>(Hbuf, Hbuf + (size_t)N_NODES * 160, 160, FXD2, 160,
                                                    dinv, base, esrc, enorm, Abuf);
    mfma_conv<160><<<dim3(NN2 / 128, 4, 1), 256, 0, stream>>>(Abuf, W3T, bc3, Hbuf, FXD4, 320);

    // pool (2048 graphs) + fc
    seg_max_bf<<<dim3(2, 2048, 1), 256, 0, stream>>>(Hbuf, pool, FXD4, 320);
    gemv_rows4<true><<<2048 / 4, 256, 0, stream>>>(pool, Wg1, bg1, nullptr, gb, FXD4, FXD2, FXD2, 0);
    gemv_rows4<false><<<2048 / 4, 256, 0, stream>>>(gb, Wg2, bg2, nullptr, xc, FXD2, OD, 384, OD);

    // ================= final MLP =================
    gemv_rows4<true><<<B_GRAPH / 4, 256, 0, stream>>>(xc, Wf1, bf1, nullptr, f1, 384, 512, 512, 0);
    gemv_rows4<true><<<B_GRAPH / 4, 256, 0, stream>>>(f1, Wf2, bf2, nullptr, f2, 512, OD, OD, 0);
    final_linear2<<<(B_GRAPH * 2 + 255) / 256, 256, 0, stream>>>(f2, Wo, bo, out);
}